// Round 11
// baseline (78.422 us; speedup 1.0000x reference)
//
#include <hip/hip_runtime.h>
#include <cmath>

#define BB 8
#define CC 128
#define NN 16384
#define HH 4
#define NB1 32                   // fuse1 blocks per batch (512 n each)
#define NB2 64                   // pass2 blocks per batch (256 n each)
#define SX 272                   // XT row stride in bytes (17 x 16B, bank-skewed)

typedef __attribute__((ext_vector_type(8))) short bf16x8;
typedef __attribute__((ext_vector_type(4))) float f32x4;

#define MFMA(a, b, c) __builtin_amdgcn_mfma_f32_16x16x32_bf16(a, b, c, 0, 0, 0)

// fp32 -> bf16 (RNE)
__device__ __forceinline__ unsigned short f2b(float f) {
  union { float f; unsigned u; } v; v.f = f;
  unsigned r = v.u + 0x7FFFu + ((v.u >> 16) & 1u);
  return (unsigned short)(r >> 16);
}

// XT addressing: [n][c] bf16, SX-byte rows, 16B block index = c/8, XOR'd with (n>>2)&7
__device__ __forceinline__ int xt_addr(int n, int cblk) {
  return n * SX + ((cblk ^ ((n >> 2) & 7)) << 4);
}
// KT/VT layout: [c][n] bf16, 144 B/row stride, XOR-swizzle on 16B blocks
__device__ __forceinline__ int kt_byte(int c, int n) {
  return c * 144 + ((((n >> 3) ^ (c & 7)) << 4) | ((n & 7) << 1));
}

// ---------------------------------------------------------------------------
// K0: convert Wq,Wk,Wv,Wo fp32[128][128] -> bf16 (same layout)
// ---------------------------------------------------------------------------
__global__ void k_prep(const float* __restrict__ Wq, const float* __restrict__ Wk,
                       const float* __restrict__ Wv, const float* __restrict__ Wo,
                       unsigned short* __restrict__ Wb) {
  const int idx = blockIdx.x * 256 + threadIdx.x;   // < 65536
  const int which = idx >> 14;
  const float* src = (which == 0) ? Wq : (which == 1) ? Wk : (which == 2) ? Wv : Wo;
  Wb[idx] = f2b(src[idx & 16383]);
}

// ---------------------------------------------------------------------------
// K1 (fused, 1024 thr, 1 block/CU, 4 waves/SIMD): per (b, 512-n chunk),
// 2 stages of 256 n:
//   stage x -> XT: wave w reads c-rows [w*8,w*8+8) as FULL 1 KB granules
//   per n-half (nh = w>>3), 2 sub-tiles of 64 n:
//     K/V proj MFMA (per-nf) + per-head LN -> KT/VT[nh]; sync; partial K^T V
// Roles (rw = w&7): proj (head=rw>>1, K/V=rw&1); kv (head=rw>>1, 32n-half=rw&1)
// Epilogue: pair-reduce nh partials in LDS, 32 KB linear dump.
// LDS: XT 69632 | KT0,KT1,VT0,VT1 4x18432 = 143360 -> 1 block/CU, 16 waves
// ---------------------------------------------------------------------------
__global__ __launch_bounds__(1024, 4)
void k_fuse1(const float* __restrict__ x,
             const unsigned short* __restrict__ Wkb, const unsigned short* __restrict__ Wvb,
             const float* __restrict__ bk, const float* __restrict__ bv,
             const float* __restrict__ gK, const float* __restrict__ bK,
             const float* __restrict__ gV, const float* __restrict__ bV,
             float* __restrict__ kvp) {
  extern __shared__ char lds[];
  char* XT = lds;                       // 69632 B (256 rows x 272)
  char* KVB = lds + 69632;              // 4 x 18432 B
  float* KVS = (float*)lds;             // 64 KB, overlays XT at the end

  const int tid = threadIdx.x;
  const int lane = tid & 63;
  const int w = tid >> 6;               // 0..15
  const int b = blockIdx.y;
  const int bx = blockIdx.x;            // 0..31
  const int l15 = lane & 15, l4 = lane >> 4;

  const int nh = w >> 3, rw = w & 7;    // n-half, role
  const int ph = rw >> 1, pp = rw & 1;  // proj: head, K/V
  const int kh = rw >> 1, khalf = rw & 1;
  char* KTn = KVB + nh * 18432;
  char* VTn = KVB + 36864 + nh * 18432;

  // W fragments: row = l15 (c_out), k = ks*32 + l4*8 + j
  const unsigned short* Wsrc = pp ? Wvb : Wkb;
  bf16x8 wf[2][4];
#pragma unroll
  for (int mf = 0; mf < 2; ++mf)
#pragma unroll
    for (int ks = 0; ks < 4; ++ks)
      wf[mf][ks] = *(const bf16x8*)(Wsrc + (ph * 32 + mf * 16 + l15) * 128 + ks * 32 + l4 * 8);

  float bias[2][4], gam[2][4], bet[2][4];
  {
    const float* bsrc = pp ? bv : bk;
    const float* gsrc = pp ? gV : gK;
    const float* esrc = pp ? bV : bK;
#pragma unroll
    for (int mf = 0; mf < 2; ++mf)
#pragma unroll
      for (int r = 0; r < 4; ++r) {
        const int cg = ph * 32 + mf * 16 + l4 * 4 + r;
        bias[mf][r] = bsrc[cg]; gam[mf][r] = gsrc[cg]; bet[mf][r] = esrc[cg];
      }
  }

  f32x4 kvacc[2][2];
#pragma unroll
  for (int i = 0; i < 2; ++i)
#pragma unroll
    for (int j = 0; j < 2; ++j) kvacc[i][j] = (f32x4){0.f, 0.f, 0.f, 0.f};

  for (int ot = 0; ot < 2; ++ot) {
    const int n0 = (bx * 2 + ot) * 256;

    // Phase 1: stage 128c x 256n of x -> XT. Wave w owns c-rows [w*8, w*8+8);
    // each row read as one wave-wide 1 KB contiguous load (16 B/lane).
    {
      const float* xb = x + ((size_t)b * CC + w * 8) * NN + n0 + lane * 4;
      f32x4 va[8];
#pragma unroll
      for (int cc = 0; cc < 8; ++cc) va[cc] = *(const f32x4*)(xb + (size_t)cc * NN);
#pragma unroll
      for (int j = 0; j < 4; ++j) {
        const int n = lane * 4 + j;
        bf16x8 pk;
#pragma unroll
        for (int cc = 0; cc < 8; ++cc)
          ((unsigned short*)&pk)[cc] = f2b(va[cc][j]);
        *(bf16x8*)(XT + n * SX + ((w ^ ((n >> 2) & 7)) << 4)) = pk;
      }
    }
    __syncthreads();

    // Phase 2: per n-half, two 64-n sub-tiles: proj per-nf + LN + kv
    for (int t = 0; t < 2; ++t) {
      const int nbase = nh * 128 + t * 64;
      char* DST = pp ? VTn : KTn;
#pragma unroll
      for (int nf = 0; nf < 4; ++nf) {
        const int n = nbase + nf * 16 + l15;
        f32x4 a0 = (f32x4){0.f, 0.f, 0.f, 0.f}, a1 = (f32x4){0.f, 0.f, 0.f, 0.f};
#pragma unroll
        for (int ks = 0; ks < 4; ++ks) {
          const bf16x8 xf = *(const bf16x8*)(XT + xt_addr(n, ks * 4 + l4));
          a0 = MFMA(wf[0][ks], xf, a0);
          a1 = MFMA(wf[1][ks], xf, a1);
        }
#pragma unroll
        for (int r = 0; r < 4; ++r) { a0[r] += bias[0][r]; a1[r] += bias[1][r]; }
        float s = 0.f, ss = 0.f;
#pragma unroll
        for (int r = 0; r < 4; ++r) {
          s += a0[r] + a1[r];
          ss += a0[r] * a0[r] + a1[r] * a1[r];
        }
        s += __shfl_xor(s, 16); ss += __shfl_xor(ss, 16);
        s += __shfl_xor(s, 32); ss += __shfl_xor(ss, 32);
        const float mu = s * (1.f / 32.f);
        const float var = ss * (1.f / 32.f) - mu * mu;
        const float rstd = rsqrtf(var + 1e-5f);
        const int nloc = nf * 16 + l15;
#pragma unroll
        for (int r = 0; r < 4; ++r) {
          const int c0k = ph * 32 + l4 * 4 + r;
          *(unsigned short*)(DST + kt_byte(c0k, nloc)) =
              f2b((a0[r] - mu) * rstd * gam[0][r] + bet[0][r]);
          const int c1k = ph * 32 + 16 + l4 * 4 + r;
          *(unsigned short*)(DST + kt_byte(c1k, nloc)) =
              f2b((a1[r] - mu) * rstd * gam[1][r] + bet[1][r]);
        }
      }
      __syncthreads();

      // kv partial += K^T V over this wave's 32-n half of its 64-n sub-tile
#pragma unroll
      for (int mf = 0; mf < 2; ++mf) {
        const int ck = kh * 32 + mf * 16 + l15;
        const bf16x8 ka = *(const bf16x8*)(KTn + ck * 144 + (((khalf * 4 + l4) ^ (ck & 7)) << 4));
#pragma unroll
        for (int ef = 0; ef < 2; ++ef) {
          const int cv = kh * 32 + ef * 16 + l15;
          const bf16x8 vb = *(const bf16x8*)(VTn + cv * 144 + (((khalf * 4 + l4) ^ (cv & 7)) << 4));
          kvacc[mf][ef] = MFMA(ka, vb, kvacc[mf][ef]);
        }
      }
      __syncthreads();   // KT/VT (and XT on last t) safe to overwrite
    }
  }

  // Epilogue: KVS[w][1024] (overlays dead XT), pair-reduce nh, 32 KB dump
#pragma unroll
  for (int mf = 0; mf < 2; ++mf)
#pragma unroll
    for (int ef = 0; ef < 2; ++ef)
#pragma unroll
      for (int r = 0; r < 4; ++r) {
        const int d = mf * 16 + l4 * 4 + r, e = ef * 16 + l15;
        KVS[w * 1024 + d * 32 + e] = kvacc[mf][ef][r];
      }
  __syncthreads();
  {
    float* og = kvp + ((size_t)(b * NB1 + bx)) * 8192;
#pragma unroll
    for (int i = 0; i < 2; ++i) {
      const int off = i * 4096 + tid * 4;
      const f32x4 v0 = *(const f32x4*)(KVS + off);          // nh = 0 (w 0..7)
      const f32x4 v1 = *(const f32x4*)(KVS + off + 8192);   // nh = 1 (w 8..15)
      *(f32x4*)(og + off) = v0 + v1;
    }
  }
}

// ---------------------------------------------------------------------------
// K2: kv reduce over 32 blocks x 2 khalf slots (fixed order), scale,
//     store kvT[b][h][e][d] bf16
// ---------------------------------------------------------------------------
__global__ void k_reduce(const float* __restrict__ kvp, unsigned short* __restrict__ kvT,
                         const float scale) {
  const int bh = blockIdx.x;            // b*4+h, 32 blocks
  const int h = bh & 3, b = bh >> 2;
  const int i = threadIdx.x;            // 0..1023 -> d*32+e
  const float* base = kvp + (size_t)b * NB1 * 8192 + i;
  float acc = 0.f;
  for (int bx = 0; bx < NB1; ++bx) {
    acc += base[(size_t)bx * 8192 + (2 * h) * 1024];
    acc += base[(size_t)bx * 8192 + (2 * h + 1) * 1024];
  }
  const int d = i >> 5, e = i & 31;
  kvT[(size_t)bh * 1024 + e * 32 + d] = f2b(acc * scale);
}

// ---------------------------------------------------------------------------
// K3 (proven R7/R10 structure): Q proj + attn + out-GEMM, double-buffered x
// staging from regs, amortized fragments, direct global stores.
// LDS: XT0 17408 | XT1 17408 | QS 16384 | AS 16384 = 67584 -> 2 blocks/CU
// ---------------------------------------------------------------------------
__global__ __launch_bounds__(512, 4)
void k_pass2(const float* __restrict__ x,
             const unsigned short* __restrict__ Wqb, const float* __restrict__ bq,
             const unsigned short* __restrict__ kvT,
             const unsigned short* __restrict__ Wob, const float* __restrict__ bo,
             float* __restrict__ out) {
  extern __shared__ char lds[];
  char* QS = lds + 34816;    // 16384  q as [n][c]
  char* AS = lds + 51200;    // 16384  attn out as [n][c']

  const int tid = threadIdx.x;
  const int lane = tid & 63;
  const int w = tid >> 6;
  const int b = blockIdx.y;
  const int l15 = lane & 15, l4 = lane >> 4;
  const int h = w >> 1, half = w & 1;

  // kv A-fragments (row = e, k = d) from global bf16 kvT[b][h][e][d]
  bf16x8 kvf[2];
#pragma unroll
  for (int mf = 0; mf < 2; ++mf)
    kvf[mf] = *(const bf16x8*)(kvT + (((size_t)b * HH + h) * 32 + mf * 16 + l15) * 32 + l4 * 8);
  bf16x8 wq[4], wo[4];
#pragma unroll
  for (int ks = 0; ks < 4; ++ks) {
    wq[ks] = *(const bf16x8*)(Wqb + (w * 16 + l15) * 128 + ks * 32 + l4 * 8);
    wo[ks] = *(const bf16x8*)(Wob + (w * 16 + l15) * 128 + ks * 32 + l4 * 8);
  }
  float bq_r[4], bo_r[4];
#pragma unroll
  for (int r = 0; r < 4; ++r) {
    bq_r[r] = bq[w * 16 + l4 * 4 + r];
    bo_r[r] = bo[w * 16 + l4 * 4 + r];
  }

  const int half2 = lane >> 5;
  const int cb2 = w * 2 + half2;        // c-block 0..15
  const int nn = (lane & 31) * 2;
  const float* xrow = x + ((size_t)b * CC + cb2 * 8) * NN + blockIdx.x * 256 + nn;
  float* ob = out + (size_t)b * CC * NN;

  float2 rx[8];
#pragma unroll
  for (int cc = 0; cc < 8; ++cc) rx[cc] = *(const float2*)(xrow + (size_t)cc * NN);

  for (int it = 0; it < 4; ++it) {
    const int n0 = blockIdx.x * 256 + it * 64;
    char* XT = (it & 1) ? (lds + 17408) : lds;

    // stage tile from regs + prefetch next
#pragma unroll
    for (int j = 0; j < 2; ++j) {
      const int n = nn + j;
      bf16x8 pk;
#pragma unroll
      for (int cc = 0; cc < 8; ++cc)
        ((unsigned short*)&pk)[cc] = f2b(j ? rx[cc].y : rx[cc].x);
      *(bf16x8*)(XT + n * SX + ((cb2 ^ ((n >> 2) & 7)) << 4)) = pk;
    }
    if (it < 3) {
      const float* xn = xrow + (it + 1) * 64;
#pragma unroll
      for (int cc = 0; cc < 8; ++cc) rx[cc] = *(const float2*)(xn + (size_t)cc * NN);
    }
    __syncthreads();

    // Phase B: q-GEMM, D[c][n], c-slice = w*16
    f32x4 qa[4];
#pragma unroll
    for (int nf = 0; nf < 4; ++nf) qa[nf] = (f32x4){0.f, 0.f, 0.f, 0.f};
#pragma unroll
    for (int ks = 0; ks < 4; ++ks)
#pragma unroll
      for (int nf = 0; nf < 4; ++nf) {
        const int n = nf * 16 + l15;
        const bf16x8 xf = *(const bf16x8*)(XT + xt_addr(n, ks * 4 + l4));
        qa[nf] = MFMA(wq[ks], xf, qa[nf]);
      }
#pragma unroll
    for (int nf = 0; nf < 4; ++nf) {
      const int n = nf * 16 + l15;
      const int c0 = w * 16 + l4 * 4;
      unsigned long long pk = 0;
#pragma unroll
      for (int r = 0; r < 4; ++r)
        pk |= (unsigned long long)f2b(qa[nf][r] + bq_r[r]) << (16 * r);
      *(unsigned long long*)(QS + n * 256 + (((c0 >> 3) ^ (n & 15)) << 4) + ((c0 & 7) << 1)) = pk;
    }
    __syncthreads();

    // Phase C: attn D[e][n] = kv(as A) * q(as B), per (head, n-half)
    f32x4 aa[2][2];
#pragma unroll
    for (int i = 0; i < 2; ++i)
#pragma unroll
      for (int j = 0; j < 2; ++j) aa[i][j] = (f32x4){0.f, 0.f, 0.f, 0.f};
    bf16x8 qf[2];
#pragma unroll
    for (int nf = 0; nf < 2; ++nf) {
      const int n = half * 32 + nf * 16 + l15;
      const int cq = h * 32 + l4 * 8;
      qf[nf] = *(const bf16x8*)(QS + n * 256 + ((((cq >> 3)) ^ (n & 15)) << 4));
    }
#pragma unroll
    for (int mf = 0; mf < 2; ++mf)
#pragma unroll
      for (int nf = 0; nf < 2; ++nf) aa[mf][nf] = MFMA(kvf[mf], qf[nf], aa[mf][nf]);
#pragma unroll
    for (int mf = 0; mf < 2; ++mf)
#pragma unroll
      for (int nf = 0; nf < 2; ++nf) {
        const int n = half * 32 + nf * 16 + l15;
        const int e0 = h * 32 + mf * 16 + l4 * 4;
        unsigned long long pk = 0;
#pragma unroll
        for (int r = 0; r < 4; ++r)
          pk |= (unsigned long long)f2b(aa[mf][nf][r]) << (16 * r);
        *(unsigned long long*)(AS + n * 256 + (((e0 >> 3) ^ (n & 15)) << 4) + ((e0 & 7) << 1)) = pk;
      }
    __syncthreads();

    // Phase D: out-GEMM, D[c_out][n], direct global stores
    f32x4 oa[4];
#pragma unroll
    for (int nf = 0; nf < 4; ++nf) oa[nf] = (f32x4){0.f, 0.f, 0.f, 0.f};
#pragma unroll
    for (int ks = 0; ks < 4; ++ks)
#pragma unroll
      for (int nf = 0; nf < 4; ++nf) {
        const int n = nf * 16 + l15;
        const bf16x8 af = *(const bf16x8*)(AS + n * 256 + (((ks * 4 + l4) ^ (n & 15)) << 4));
        oa[nf] = MFMA(wo[ks], af, oa[nf]);
      }
#pragma unroll
    for (int nf = 0; nf < 4; ++nf)
#pragma unroll
      for (int r = 0; r < 4; ++r) {
        const int c = w * 16 + l4 * 4 + r;
        ob[(size_t)c * NN + n0 + nf * 16 + l15] = oa[nf][r] + bo_r[r];
      }
  }
}

// ---------------------------------------------------------------------------
extern "C" void kernel_launch(void* const* d_in, const int* in_sizes, int n_in,
                              void* d_out, int out_size, void* d_ws, size_t ws_size,
                              hipStream_t stream) {
  const float* x  = (const float*)d_in[0];
  const float* Wq = (const float*)d_in[1];
  const float* bq = (const float*)d_in[2];
  const float* Wk = (const float*)d_in[3];
  const float* bk = (const float*)d_in[4];
  const float* Wv = (const float*)d_in[5];
  const float* bv = (const float*)d_in[6];
  const float* gK = (const float*)d_in[7];
  const float* bK = (const float*)d_in[8];
  const float* gV = (const float*)d_in[9];
  const float* bV = (const float*)d_in[10];
  const float* Wo = (const float*)d_in[11];
  const float* bo = (const float*)d_in[12];
  float* out = (float*)d_out;

  char* ws = (char*)d_ws;
  float* kvp = (float*)ws;                                   // 8*32*8192 f32 = 8 MB
  unsigned short* kvTb = (unsigned short*)(ws + (size_t)BB * NB1 * 8192 * 4); // 64 KB
  unsigned short* Wb = kvTb + (size_t)BB * HH * 1024;        // 128 KB
  const unsigned short* Wqb = Wb;
  const unsigned short* Wkb = Wb + 16384;
  const unsigned short* Wvb = Wb + 32768;
  const unsigned short* Wob = Wb + 49152;

  (void)hipFuncSetAttribute(reinterpret_cast<const void*>(k_fuse1),
                            hipFuncAttributeMaxDynamicSharedMemorySize, 143360);
  (void)hipFuncSetAttribute(reinterpret_cast<const void*>(k_pass2),
                            hipFuncAttributeMaxDynamicSharedMemorySize, 67584);

  k_prep<<<256, 256, 0, stream>>>(Wq, Wk, Wv, Wo, Wb);

  k_fuse1<<<dim3(NB1, BB), 1024, 143360, stream>>>(
      x, Wkb, Wvb, bk, bv, gK, bK, gV, bV, kvp);

  const float scale = 1.0f / (5.65685424949238f * 16384.0f);  // 1/(sqrt(32)*N)
  k_reduce<<<32, 1024, 0, stream>>>(kvp, kvTb, scale);

  k_pass2<<<dim3(NB2, BB), 512, 67584, stream>>>(
      x, Wqb, bq, kvTb, Wob, bo, out);
}